// Round 2
// baseline (45483.267 us; speedup 1.0000x reference)
//
#include <hip/hip_runtime.h>
#include <math.h>

#define NB 128
#define NITEMS 8192
#define NHID 256
#define NLAT 64
#define NEMB_ 512
#define NQ_ 4
#define LENC 4096
#define LDEC 8192
#define NROWS 524288            // NB*NLAT*LENC/64
#define VQ_NELEM 33554432.0f    // NB*NLAT*LENC

// ---------------------------------------------------------------- small prep
__global__ void k_zero(float* __restrict__ p, int n){
  int i = blockIdx.x*256 + threadIdx.x;
  if(i < n) p[i] = 0.f;
}

__global__ void k_gather(const int* __restrict__ uid, const float* __restrict__ mat,
                         float* __restrict__ x){
  int b = blockIdx.y;
  int i = blockIdx.x*256 + threadIdx.x;
  x[(size_t)b*NITEMS + i] = mat[(size_t)uid[b]*NITEMS + i];
}

// w[CO][CI][K] -> wp[k][ci][co]
__global__ void k_pack_ocik(const float* __restrict__ w, float* __restrict__ wp,
                            int CO, int CI, int K){
  int idx = blockIdx.x*256 + threadIdx.x;
  int n = CO*CI*K;
  if(idx >= n) return;
  int k  = idx % K;
  int ci = (idx / K) % CI;
  int co = idx / (K*CI);
  wp[((size_t)k*CI + ci)*CO + co] = w[idx];
}

// w[CI][CO][K] -> wp[k][ci][co]  (ConvTranspose layout)
__global__ void k_pack_icok(const float* __restrict__ w, float* __restrict__ wp,
                            int CI, int CO, int K){
  int idx = blockIdx.x*256 + threadIdx.x;
  int n = CI*CO*K;
  if(idx >= n) return;
  int k  = idx % K;
  int co = (idx / K) % CO;
  int ci = idx / (K*CO);
  wp[((size_t)k*CI + ci)*CO + co] = w[idx];
}

__global__ void k_cbprep(const float* __restrict__ cb, float* __restrict__ cbs){
  int idx = blockIdx.x*256 + threadIdx.x;   // NQ*NEMB*64 total
  cbs[idx] = -2.0f*cb[idx];
}

__global__ void k_cbnorm(const float* __restrict__ cb, float* __restrict__ cb2){
  int idx = blockIdx.x*256 + threadIdx.x;
  if(idx >= NQ_*NEMB_) return;
  const float* p = cb + (size_t)idx*64;
  float s = 0.f;
  #pragma unroll
  for(int d=0; d<64; d++) s = fmaf(p[d], p[d], s);
  cb2[idx] = s;
}

// ------------------------------------------------- encoder first conv (C_in=1)
// out[b,co,l] = relu(bias + sum_k w[co,0,k]*x[b, 2l-1+k]), L_out = 4096
__global__ void k_enc0(const float* __restrict__ x, const float* __restrict__ w,
                       const float* __restrict__ bias, float* __restrict__ out){
  int l  = blockIdx.x*256 + threadIdx.x;
  int co = blockIdx.y;
  int b  = blockIdx.z;
  const float* xr = x + (size_t)b*NITEMS;
  float acc = bias[co];
  int base = 2*l - 1;
  #pragma unroll
  for(int k=0; k<4; k++){
    int i = base + k;
    float xv = (i >= 0 && i < NITEMS) ? xr[i] : 0.f;
    acc = fmaf(w[co*4+k], xv, acc);
  }
  out[((size_t)b*NHID + co)*LENC + l] = fmaxf(acc, 0.f);
}

// ------------------------------------------------------------- conv K=3 pad=1
#define C3_LT  128
#define C3_COT 64
#define C3_CIC 32
// wp packed [k][ci][co]; out[b,co,l] = (relu?)(bias + sum_{ci,k} w*in[b,ci,l-1+k])
__global__ __launch_bounds__(256) void k_conv3(
    const float* __restrict__ in, const float* __restrict__ wp,
    const float* __restrict__ bias, float* __restrict__ out,
    int CIN, int COUT, int L, int do_relu){
  __shared__ float s_in[C3_CIC][C3_LT+8];
  __shared__ float s_w[3][C3_CIC][C3_COT];
  const int tid = threadIdx.x;
  const int b = blockIdx.z;
  const int co_base = blockIdx.y*C3_COT;
  const int l_base  = blockIdx.x*C3_LT;
  const int co_grp  = tid>>5;        // 0..7  (8 co each)
  const int dl      = (tid&31)*4;    // 0..124 (4 l each)
  float acc[8][4];
  #pragma unroll
  for(int c=0;c<8;c++)
    #pragma unroll
    for(int j=0;j<4;j++) acc[c][j]=0.f;

  for(int cib=0; cib<CIN; cib+=C3_CIC){
    #pragma unroll
    for(int t=0;t<17;t++){                       // 32*136/256 = 17
      int idx = tid + t*256;
      int ci = idx/(C3_LT+8);
      int jj = idx%(C3_LT+8);
      int l = l_base - 4 + jj;                   // s_in[ci][jj] <-> l = l_base-4+jj
      float v = 0.f;
      if(l>=0 && l<L) v = in[((size_t)b*CIN + cib + ci)*L + l];
      s_in[ci][jj] = v;
    }
    #pragma unroll
    for(int t=0;t<24;t++){                       // 3*32*64/256 = 24
      int idx = tid + t*256;
      int k  = idx/(C3_CIC*C3_COT);
      int rr = idx%(C3_CIC*C3_COT);
      int ci = rr/C3_COT, co = rr%C3_COT;
      s_w[k][ci][co] = wp[((size_t)k*CIN + cib + ci)*COUT + co_base + co];
    }
    __syncthreads();
    for(int ci=0; ci<C3_CIC; ci++){
      float xm1 = s_in[ci][dl+3];                       // l0-1
      float4 xm = *(const float4*)&s_in[ci][dl+4];      // l0..l0+3
      float xp4 = s_in[ci][dl+8];                       // l0+4
      float xv[6] = {xm1, xm.x, xm.y, xm.z, xm.w, xp4}; // xv[i] = in[l0-1+i]
      #pragma unroll
      for(int k=0;k<3;k++){
        float4 w0 = *(const float4*)&s_w[k][ci][co_grp*8];
        float4 w1 = *(const float4*)&s_w[k][ci][co_grp*8+4];
        float wv[8]={w0.x,w0.y,w0.z,w0.w,w1.x,w1.y,w1.z,w1.w};
        #pragma unroll
        for(int c=0;c<8;c++)
          #pragma unroll
          for(int j=0;j<4;j++)
            acc[c][j] = fmaf(wv[c], xv[j+k], acc[c][j]);
      }
    }
    __syncthreads();
  }
  #pragma unroll
  for(int c=0;c<8;c++){
    int co = co_base + co_grp*8 + c;
    float bv = bias[co];
    size_t base = ((size_t)b*COUT + co)*L + l_base + dl;
    float4 o;
    o.x = acc[c][0]+bv; o.y = acc[c][1]+bv; o.z = acc[c][2]+bv; o.w = acc[c][3]+bv;
    if(do_relu){ o.x=fmaxf(o.x,0.f); o.y=fmaxf(o.y,0.f); o.z=fmaxf(o.z,0.f); o.w=fmaxf(o.w,0.f); }
    *(float4*)&out[base] = o;
  }
}

// --------------------------------------------- conv 1x1 + residual add + relu
// wt packed [ci][co]; out = relu(bias + res + sum_ci wt*in). out==res is safe.
__global__ __launch_bounds__(256) void k_conv1(
    const float* __restrict__ in, const float* __restrict__ wt,
    const float* __restrict__ bias, const float* __restrict__ res,
    float* __restrict__ out, int CIN, int COUT, int L){
  __shared__ float s_in[C3_CIC][C3_LT];
  __shared__ float s_w[C3_CIC][C3_COT];
  const int tid = threadIdx.x;
  const int b = blockIdx.z;
  const int co_base = blockIdx.y*C3_COT;
  const int l_base  = blockIdx.x*C3_LT;
  const int co_grp  = tid>>5;
  const int dl      = (tid&31)*4;
  float acc[8][4];
  #pragma unroll
  for(int c=0;c<8;c++)
    #pragma unroll
    for(int j=0;j<4;j++) acc[c][j]=0.f;

  for(int cib=0; cib<CIN; cib+=C3_CIC){
    #pragma unroll
    for(int t=0;t<16;t++){
      int idx = tid + t*256;
      int ci = idx>>7, l = idx&127;
      s_in[ci][l] = in[((size_t)b*CIN + cib + ci)*L + l_base + l];
    }
    #pragma unroll
    for(int t=0;t<8;t++){
      int idx = tid + t*256;
      int ci = idx>>6, co = idx&63;
      s_w[ci][co] = wt[(size_t)(cib+ci)*COUT + co_base + co];
    }
    __syncthreads();
    for(int ci=0; ci<C3_CIC; ci++){
      float4 xm = *(const float4*)&s_in[ci][dl];
      float4 w0 = *(const float4*)&s_w[ci][co_grp*8];
      float4 w1 = *(const float4*)&s_w[ci][co_grp*8+4];
      float wv[8]={w0.x,w0.y,w0.z,w0.w,w1.x,w1.y,w1.z,w1.w};
      float xv[4]={xm.x,xm.y,xm.z,xm.w};
      #pragma unroll
      for(int c=0;c<8;c++)
        #pragma unroll
        for(int j=0;j<4;j++)
          acc[c][j] = fmaf(wv[c], xv[j], acc[c][j]);
    }
    __syncthreads();
  }
  #pragma unroll
  for(int c=0;c<8;c++){
    int co = co_base + co_grp*8 + c;
    float bv = bias[co];
    size_t base = ((size_t)b*COUT + co)*L + l_base + dl;
    float4 rv = *(const float4*)&res[base];
    float4 o;
    o.x = fmaxf(acc[c][0]+bv+rv.x, 0.f);
    o.y = fmaxf(acc[c][1]+bv+rv.y, 0.f);
    o.z = fmaxf(acc[c][2]+bv+rv.z, 0.f);
    o.w = fmaxf(acc[c][3]+bv+rv.w, 0.f);
    *(float4*)&out[base] = o;
  }
}

// --------------------------------------------------- residual-VQ (all 4 stages)
// one thread per 64-elem row (torch view(-1,64): 64 consecutive L positions)
__global__ __launch_bounds__(256) void k_vq(
    const float* __restrict__ z_e, const float* __restrict__ cb,
    const float* __restrict__ cbs, const float* __restrict__ cb2,
    float* __restrict__ z_q, float* __restrict__ loss, int* __restrict__ counts){
  __shared__ int hist[NQ_][NEMB_];
  const int tid = threadIdx.x;
  for(int i=tid;i<NQ_*NEMB_;i+=256) (&hist[0][0])[i]=0;
  __syncthreads();

  const size_t row = (size_t)blockIdx.x*256 + tid;
  const float4* zp = (const float4*)(z_e + row*64);
  float r[64];
  #pragma unroll
  for(int i=0;i<16;i++){
    float4 v = zp[i];
    r[4*i+0]=v.x; r[4*i+1]=v.y; r[4*i+2]=v.z; r[4*i+3]=v.w;
  }

  #pragma unroll 1
  for(int q=0;q<NQ_;q++){
    float a0=0.f,a1=0.f,a2=0.f,a3=0.f;
    #pragma unroll
    for(int d=0;d<64;d+=4){
      a0=fmaf(r[d+0],r[d+0],a0); a1=fmaf(r[d+1],r[d+1],a1);
      a2=fmaf(r[d+2],r[d+2],a2); a3=fmaf(r[d+3],r[d+3],a3);
    }
    float rsq=(a0+a1)+(a2+a3);

    const float* cq  = cbs + (size_t)q*NEMB_*64;
    const float* c2q = cb2 + (size_t)q*NEMB_;
    float best=3.0e38f; int bi=0;
    #pragma unroll 2
    for(int c=0;c<NEMB_;c++){
      const float* cc = cq + c*64;           // wave-uniform -> s_load stream
      float s0=c2q[c], s1=0.f, s2=0.f, s3=0.f;
      #pragma unroll
      for(int d=0;d<64;d+=4){
        s0=fmaf(cc[d+0],r[d+0],s0);
        s1=fmaf(cc[d+1],r[d+1],s1);
        s2=fmaf(cc[d+2],r[d+2],s2);
        s3=fmaf(cc[d+3],r[d+3],s3);
      }
      float sc=(s0+s1)+(s2+s3);              // |c|^2 - 2 r.c
      if(sc<best){best=sc;bi=c;}             // strict < keeps first index on ties
    }
    // stage loss: sum((quant-r)^2) = |r|^2 + best
    float sl = rsq + best;
    #pragma unroll
    for(int off=32;off;off>>=1) sl += __shfl_down(sl, off);
    if((tid&63)==0) atomicAdd(&loss[q], sl);
    atomicAdd(&hist[q][bi], 1);
    // r -= quant
    const float4* qp = (const float4*)(cb + ((size_t)q*NEMB_ + bi)*64);
    #pragma unroll
    for(int i=0;i<16;i++){
      float4 v = qp[i];
      r[4*i+0]-=v.x; r[4*i+1]-=v.y; r[4*i+2]-=v.z; r[4*i+3]-=v.w;
    }
  }
  // z_q = z_e - final residual
  float4* oq = (float4*)(z_q + row*64);
  #pragma unroll
  for(int i=0;i<16;i++){
    float4 v = zp[i];
    float4 w;
    w.x=v.x-r[4*i+0]; w.y=v.y-r[4*i+1]; w.z=v.z-r[4*i+2]; w.w=v.w-r[4*i+3];
    oq[i]=w;
  }
  __syncthreads();
  for(int i=tid;i<NQ_*NEMB_;i+=256){
    int v=(&hist[0][0])[i];
    if(v) atomicAdd(&counts[i], v);
  }
}

// -------------------------------- ConvTranspose1d K=4 s=2 p=1 (64->256) + relu
// even j=2t:  sum_ci w[ci,co,1]*x[t]   + w[ci,co,3]*x[t-1]
// odd  j=2t+1:sum_ci w[ci,co,2]*x[t]   + w[ci,co,0]*x[t+1]
__global__ __launch_bounds__(256) void k_convT(
    const float* __restrict__ zq, const float* __restrict__ wp,  // wp[k][ci][co]
    const float* __restrict__ bias, float* __restrict__ out){
  __shared__ float s_in[32][72];
  __shared__ float s_w[4][32][64];
  const int tid = threadIdx.x;
  const int b = blockIdx.z;
  const int co_base = blockIdx.y*64;
  const int t_base  = blockIdx.x*64;
  const int co_grp  = tid>>4;        // 0..15 (4 co each)
  const int dt      = (tid&15)*4;    // 0..60 (4 t each)
  float ae[4][4], ao[4][4];
  #pragma unroll
  for(int c=0;c<4;c++)
    #pragma unroll
    for(int j=0;j<4;j++){ ae[c][j]=0.f; ao[c][j]=0.f; }

  for(int cib=0; cib<NLAT; cib+=32){
    #pragma unroll
    for(int t=0;t<9;t++){                  // 32*72/256 = 9
      int idx = tid + t*256;
      int ci = idx/72, jj = idx%72;
      int tt = t_base - 4 + jj;
      float v = 0.f;
      if(tt>=0 && tt<LENC) v = zq[((size_t)b*NLAT + cib + ci)*LENC + tt];
      s_in[ci][jj] = v;
    }
    #pragma unroll
    for(int t=0;t<32;t++){                 // 4*32*64/256 = 32
      int idx = tid + t*256;
      int k  = idx>>11;
      int rr = idx&2047;
      int ci = rr>>6, co = rr&63;
      s_w[k][ci][co] = wp[((size_t)k*NLAT + cib + ci)*NHID + co_base + co];
    }
    __syncthreads();
    for(int ci=0; ci<32; ci++){
      float xm1 = s_in[ci][dt+3];
      float4 xm = *(const float4*)&s_in[ci][dt+4];
      float xp4 = s_in[ci][dt+8];
      float xv[6]={xm1, xm.x, xm.y, xm.z, xm.w, xp4};  // xv[i] = x[t0-1+i]
      float4 w0 = *(const float4*)&s_w[0][ci][co_grp*4];
      float4 w1 = *(const float4*)&s_w[1][ci][co_grp*4];
      float4 w2 = *(const float4*)&s_w[2][ci][co_grp*4];
      float4 w3 = *(const float4*)&s_w[3][ci][co_grp*4];
      float wv0[4]={w0.x,w0.y,w0.z,w0.w};
      float wv1[4]={w1.x,w1.y,w1.z,w1.w};
      float wv2[4]={w2.x,w2.y,w2.z,w2.w};
      float wv3[4]={w3.x,w3.y,w3.z,w3.w};
      #pragma unroll
      for(int c=0;c<4;c++)
        #pragma unroll
        for(int j=0;j<4;j++){
          ae[c][j] = fmaf(wv1[c], xv[j+1], ae[c][j]);
          ae[c][j] = fmaf(wv3[c], xv[j],   ae[c][j]);
          ao[c][j] = fmaf(wv2[c], xv[j+1], ao[c][j]);
          ao[c][j] = fmaf(wv0[c], xv[j+2], ao[c][j]);
        }
    }
    __syncthreads();
  }
  #pragma unroll
  for(int c=0;c<4;c++){
    int co = co_base + co_grp*4 + c;
    float bv = bias[co];
    size_t base = ((size_t)b*NHID + co)*LDEC + 2*(size_t)(t_base+dt);
    float4 o1, o2;
    o1.x=fmaxf(ae[c][0]+bv,0.f); o1.y=fmaxf(ao[c][0]+bv,0.f);
    o1.z=fmaxf(ae[c][1]+bv,0.f); o1.w=fmaxf(ao[c][1]+bv,0.f);
    o2.x=fmaxf(ae[c][2]+bv,0.f); o2.y=fmaxf(ao[c][2]+bv,0.f);
    o2.z=fmaxf(ae[c][3]+bv,0.f); o2.w=fmaxf(ao[c][3]+bv,0.f);
    *(float4*)&out[base]   = o1;
    *(float4*)&out[base+4] = o2;
  }
}

// -------------------- final ConvTranspose K=3 s=1 p=1 (256->1), no activation
// dvec[b,j] = b0 + sum_ci sum_t w[ci,0,2-t]*d[b,ci,j-1+t]
__global__ __launch_bounds__(256) void k_finalT(
    const float* __restrict__ in, const float* __restrict__ w,
    const float* __restrict__ bias, float* __restrict__ out){
  __shared__ float s_d[32][258];
  const int tid = threadIdx.x;
  const int j_base = blockIdx.x*256;
  const int b = blockIdx.y;
  float acc = bias[0];
  for(int cib=0; cib<NHID; cib+=32){
    for(int idx=tid; idx<32*258; idx+=256){
      int ci = idx/258, jj = idx%258;
      int l = j_base - 1 + jj;
      float v = 0.f;
      if(l>=0 && l<LDEC) v = in[((size_t)b*NHID + cib + ci)*LDEC + l];
      s_d[ci][jj] = v;
    }
    __syncthreads();
    for(int ci=0; ci<32; ci++){
      float wa = w[(cib+ci)*3+2];   // t=0 tap
      float wb = w[(cib+ci)*3+1];   // t=1 tap
      float wc = w[(cib+ci)*3+0];   // t=2 tap
      acc = fmaf(wa, s_d[ci][tid],   acc);
      acc = fmaf(wb, s_d[ci][tid+1], acc);
      acc = fmaf(wc, s_d[ci][tid+2], acc);
    }
    __syncthreads();
  }
  out[(size_t)b*NITEMS + j_base + tid] = acc;
}

// ------------------------------------ out projection: recon = dvec @ W^T + b
__global__ __launch_bounds__(256) void k_outproj(
    const float* __restrict__ dvec, const float* __restrict__ Wm,
    const float* __restrict__ bias, float* __restrict__ out){
  __shared__ float s_d[32][129];   // [m][b]
  __shared__ float s_w[32][65];    // [m][n]
  const int tid = threadIdx.x;
  const int n_base = blockIdx.x*64;
  const int n_grp = tid>>4;        // 0..15, n = n_grp + 16k
  const int b_grp = tid&15;        // 0..15, b = b_grp + 16j
  float acc[4][8];
  #pragma unroll
  for(int k=0;k<4;k++)
    #pragma unroll
    for(int j=0;j<8;j++) acc[k][j]=0.f;

  const int mloc = tid&31;
  const int half = tid>>5;         // 0..7
  for(int m0=0; m0<NITEMS; m0+=32){
    #pragma unroll
    for(int r=0;r<16;r++){
      int bb = half + r*8;
      s_d[mloc][bb] = dvec[(size_t)bb*NITEMS + m0 + mloc];
    }
    #pragma unroll
    for(int r=0;r<8;r++){
      int nn = half + r*8;
      s_w[mloc][nn] = Wm[(size_t)(n_base+nn)*NITEMS + m0 + mloc];
    }
    __syncthreads();
    for(int m=0;m<32;m++){
      float wv[4], dv[8];
      #pragma unroll
      for(int k=0;k<4;k++) wv[k]=s_w[m][n_grp+16*k];
      #pragma unroll
      for(int j=0;j<8;j++) dv[j]=s_d[m][b_grp+16*j];
      #pragma unroll
      for(int k=0;k<4;k++)
        #pragma unroll
        for(int j=0;j<8;j++)
          acc[k][j]=fmaf(wv[k],dv[j],acc[k][j]);
    }
    __syncthreads();
  }
  #pragma unroll
  for(int k=0;k<4;k++){
    int n = n_base + n_grp + 16*k;
    float bv = bias[n];
    #pragma unroll
    for(int j=0;j<8;j++){
      int bb = b_grp + 16*j;
      out[(size_t)bb*NITEMS + n] = acc[k][j] + bv;
    }
  }
}

// ------------------------------------------------- finalize scalars
__global__ void k_finalize(const float* __restrict__ loss, const int* __restrict__ counts,
                           float* __restrict__ out){
  __shared__ float sh[512];
  const int tid = threadIdx.x;
  float perp_sum = 0.f;
  for(int q=0;q<NQ_;q++){
    float avg = (float)counts[q*NEMB_+tid] / (float)NROWS;
    sh[tid] = avg*logf(avg + 1e-10f);
    __syncthreads();
    for(int s=256;s>0;s>>=1){ if(tid<s) sh[tid]+=sh[tid+s]; __syncthreads(); }
    if(tid==0) perp_sum += expf(-sh[0]);
    __syncthreads();
  }
  if(tid==0){
    float vl = 0.f;
    for(int q=0;q<NQ_;q++) vl += 1.25f*loss[q]/VQ_NELEM;
    out[0] = vl;
    out[1] = perp_sum/(float)NQ_;
  }
}

// =================================================================== launcher
extern "C" void kernel_launch(void* const* d_in, const int* in_sizes, int n_in,
                              void* d_out, int out_size, void* d_ws, size_t ws_size,
                              hipStream_t stream){
  (void)in_sizes; (void)n_in; (void)out_size;
  const int*   uid   = (const int*)d_in[0];
  const float* mat   = (const float*)d_in[1];
  const float* ec_w  = (const float*)d_in[2];
  const float* ec_b  = (const float*)d_in[3];
  const float* er_w1 = (const float*)d_in[4];
  const float* er_b1 = (const float*)d_in[5];
  const float* er_w2 = (const float*)d_in[6];
  const float* er_b2 = (const float*)d_in[7];
  const float* ef_w  = (const float*)d_in[8];
  const float* ef_b  = (const float*)d_in[9];
  const float* cb    = (const float*)d_in[10];
  const float* dt_w  = (const float*)d_in[11];
  const float* dt_b  = (const float*)d_in[12];
  const float* dr_w1 = (const float*)d_in[13];
  const float* dr_b1 = (const float*)d_in[14];
  const float* dr_w2 = (const float*)d_in[15];
  const float* dr_b2 = (const float*)d_in[16];
  const float* df_w  = (const float*)d_in[17];
  const float* df_b  = (const float*)d_in[18];
  const float* op_w  = (const float*)d_in[19];
  const float* op_b  = (const float*)d_in[20];
  float* outp = (float*)d_out;

  // ---------------- workspace layout: fixed region first, chunk buffers after
  float* W = (float*)d_ws;
  size_t o = 0;
  float* xg    = W + o; o += (size_t)NB*NITEMS;        // 1 Mi floats
  float* dvec  = W + o; o += (size_t)NB*NITEMS;        // 1 Mi floats
  float* wp3e0 = W + o; o += 3*NHID*NHID;
  float* wp3e1 = W + o; o += 3*NHID*NHID;
  float* wp3d0 = W + o; o += 3*NHID*NHID;
  float* wp3d1 = W + o; o += 3*NHID*NHID;
  float* wpF   = W + o; o += 3*NHID*NLAT;
  float* wp1e0 = W + o; o += NHID*NHID;
  float* wp1e1 = W + o; o += NHID*NHID;
  float* wp1d0 = W + o; o += NHID*NHID;
  float* wp1d1 = W + o; o += NHID*NHID;
  float* wpT   = W + o; o += 4*NLAT*NHID;
  float* cbs   = W + o; o += (size_t)NQ_*NEMB_*64;
  float* cb2   = W + o; o += NQ_*NEMB_;
  float* lossb = W + o; o += 4;                        // loss[4] then counts[2048], contiguous
  int*   counts= (int*)(W + o); o += NQ_*NEMB_;
  const size_t fixedF = o;

  // pick batch chunk CB (power of two <= 128) so 2 chunk buffers fit in d_ws
  const size_t perB = (size_t)NHID*LDEC;               // floats per batch elem per buffer
  size_t availF = ws_size/sizeof(float) > fixedF ? ws_size/sizeof(float) - fixedF : 0;
  int CB = 128;
  while(CB > 1 && (size_t)CB*2*perB > availF) CB >>= 1;

  // zero loss + counts
  k_zero<<<(4 + NQ_*NEMB_ + 255)/256,256,0,stream>>>(lossb, 4 + NQ_*NEMB_);

  // weight repacks + codebook prep (once)
  k_pack_ocik<<<(3*NHID*NHID+255)/256,256,0,stream>>>(er_w1,               wp3e0, NHID, NHID, 3);
  k_pack_ocik<<<(3*NHID*NHID+255)/256,256,0,stream>>>(er_w1+3*NHID*NHID,   wp3e1, NHID, NHID, 3);
  k_pack_ocik<<<(3*NHID*NHID+255)/256,256,0,stream>>>(dr_w1,               wp3d0, NHID, NHID, 3);
  k_pack_ocik<<<(3*NHID*NHID+255)/256,256,0,stream>>>(dr_w1+3*NHID*NHID,   wp3d1, NHID, NHID, 3);
  k_pack_ocik<<<(3*NHID*NLAT+255)/256,256,0,stream>>>(ef_w,                wpF,   NLAT, NHID, 3);
  k_pack_ocik<<<(NHID*NHID+255)/256,256,0,stream>>>(er_w2,                 wp1e0, NHID, NHID, 1);
  k_pack_ocik<<<(NHID*NHID+255)/256,256,0,stream>>>(er_w2+NHID*NHID,       wp1e1, NHID, NHID, 1);
  k_pack_ocik<<<(NHID*NHID+255)/256,256,0,stream>>>(dr_w2,                 wp1d0, NHID, NHID, 1);
  k_pack_ocik<<<(NHID*NHID+255)/256,256,0,stream>>>(dr_w2+NHID*NHID,       wp1d1, NHID, NHID, 1);
  k_pack_icok<<<(4*NLAT*NHID+255)/256,256,0,stream>>>(dt_w,                wpT,   NLAT, NHID, 4);
  k_cbprep<<<(NQ_*NEMB_*64)/256,256,0,stream>>>(cb, cbs);
  k_cbnorm<<<(NQ_*NEMB_+255)/256,256,0,stream>>>(cb, cb2);

  // gather full batch interactions (4 MB)
  k_gather<<<dim3(NITEMS/256, NB),256,0,stream>>>(uid, mat, xg);

  // chunk buffers (each CB*NHID*LDEC floats)
  float* D0 = W + fixedF;
  float* D1 = D0 + (size_t)CB*perB;

  for(int c0 = 0; c0 < NB; c0 += CB){
    // encoder buffers alias D0 (each CB*NHID*LENC = half of D0)
    float* Abuf = D0;
    float* Bbuf = D0 + (size_t)CB*NHID*LENC;
    // z_e / z_q alias D1 (each CB*NLAT*LENC = 1/8 of D1)
    float* z_e = D1;
    float* z_q = D1 + (size_t)CB*NLAT*LENC;
    const float* xgc = xg + (size_t)c0*NITEMS;
    float* dvc = dvec + (size_t)c0*NITEMS;

    // encoder
    k_enc0<<<dim3(LENC/256, NHID, CB),256,0,stream>>>(xgc, ec_w, ec_b, Abuf);
    k_conv3<<<dim3(LENC/C3_LT, NHID/C3_COT, CB),256,0,stream>>>(Abuf, wp3e0, er_b1,      Bbuf, NHID, NHID, LENC, 1);
    k_conv1<<<dim3(LENC/C3_LT, NHID/C3_COT, CB),256,0,stream>>>(Bbuf, wp1e0, er_b2,      Abuf, Abuf, NHID, NHID, LENC);
    k_conv3<<<dim3(LENC/C3_LT, NHID/C3_COT, CB),256,0,stream>>>(Abuf, wp3e1, er_b1+NHID, Bbuf, NHID, NHID, LENC, 1);
    k_conv1<<<dim3(LENC/C3_LT, NHID/C3_COT, CB),256,0,stream>>>(Bbuf, wp1e1, er_b2+NHID, Abuf, Abuf, NHID, NHID, LENC);
    k_conv3<<<dim3(LENC/C3_LT, NLAT/C3_COT, CB),256,0,stream>>>(Abuf, wpF,   ef_b,       z_e,  NHID, NLAT, LENC, 0);

    // residual VQ (rows = CB*NLAT*LENC/64 = CB*4096; 4096%256==0)
    k_vq<<<(CB*NLAT*LENC/64)/256,256,0,stream>>>(z_e, cb, cbs, cb2, z_q, lossb, counts);

    // decoder
    k_convT<<<dim3(LENC/64, NHID/64, CB),256,0,stream>>>(z_q, wpT, dt_b, D0);
    k_conv3<<<dim3(LDEC/C3_LT, NHID/C3_COT, CB),256,0,stream>>>(D0, wp3d0, dr_b1,      D1, NHID, NHID, LDEC, 1);
    k_conv1<<<dim3(LDEC/C3_LT, NHID/C3_COT, CB),256,0,stream>>>(D1, wp1d0, dr_b2,      D0, D0, NHID, NHID, LDEC);
    k_conv3<<<dim3(LDEC/C3_LT, NHID/C3_COT, CB),256,0,stream>>>(D0, wp3d1, dr_b1+NHID, D1, NHID, NHID, LDEC, 1);
    k_conv1<<<dim3(LDEC/C3_LT, NHID/C3_COT, CB),256,0,stream>>>(D1, wp1d1, dr_b2+NHID, D0, D0, NHID, NHID, LDEC);
    k_finalT<<<dim3(LDEC/256, CB),256,0,stream>>>(D0, df_w, df_b, dvc);
  }

  // head + scalars (full batch)
  k_outproj<<<NITEMS/64,256,0,stream>>>(dvec, op_w, op_b, outp);
  k_finalize<<<1,512,0,stream>>>(lossb, counts, outp + (size_t)NB*NITEMS);
}

// Round 3
// 10760.679 us; speedup vs baseline: 4.2268x; 4.2268x over previous
//
#include <hip/hip_runtime.h>
#include <math.h>

#define NB 128
#define NITEMS 8192
#define NHID 256
#define NLAT 64
#define NEMB_ 512
#define NQ_ 4
#define LENC 4096
#define LDEC 8192
#define NROWS 524288            // NB*NLAT*LENC/64
#define VQ_NELEM 33554432.0f    // NB*NLAT*LENC

typedef unsigned short u16;
typedef __attribute__((ext_vector_type(8))) short bf16x8;
typedef __attribute__((ext_vector_type(4))) float f32x4;

__device__ __forceinline__ u16 f2b(float f){
  unsigned u = __float_as_uint(f);
  unsigned r = (u + 0x7FFFu + ((u>>16)&1u)) >> 16;
  return (u16)r;
}
__device__ __forceinline__ float b2f(u16 h){
  return __uint_as_float(((unsigned)h)<<16);
}

// ---------------------------------------------------------------- small prep
__global__ void k_zero(float* __restrict__ p, int n){
  int i = blockIdx.x*256 + threadIdx.x;
  if(i < n) p[i] = 0.f;
}

__global__ void k_gather(const int* __restrict__ uid, const float* __restrict__ mat,
                         float* __restrict__ x){
  int b = blockIdx.y;
  int i = blockIdx.x*256 + threadIdx.x;
  x[(size_t)b*NITEMS + i] = mat[(size_t)uid[b]*NITEMS + i];
}

// w[CO][CI][K] f32 -> wb[k][co][ci] bf16
__global__ void k_packw(const float* __restrict__ w, u16* __restrict__ wb,
                        int CO, int CI, int K){
  int idx = blockIdx.x*256 + threadIdx.x;
  int n = CO*CI*K;
  if(idx >= n) return;
  int k  = idx % K;
  int ci = (idx / K) % CI;
  int co = idx / (K*CI);
  wb[((size_t)k*CO + co)*CI + ci] = f2b(w[idx]);
}

// ConvTranspose w[CI=64][CO=256][4] f32 -> wb[tap][co][ci] bf16
__global__ void k_packwT(const float* __restrict__ w, u16* __restrict__ wb){
  int idx = blockIdx.x*256 + threadIdx.x;
  if(idx >= 64*256*4) return;
  int k  = idx % 4;
  int co = (idx / 4) % 256;
  int ci = idx / (4*256);
  wb[((size_t)k*256 + co)*64 + ci] = f2b(w[idx]);
}

__global__ void k_cbprep(const float* __restrict__ cb, float* __restrict__ cbs){
  int idx = blockIdx.x*256 + threadIdx.x;   // NQ*NEMB*64 total
  cbs[idx] = -2.0f*cb[idx];
}

__global__ void k_cbnorm(const float* __restrict__ cb, float* __restrict__ cb2){
  int idx = blockIdx.x*256 + threadIdx.x;
  if(idx >= NQ_*NEMB_) return;
  const float* p = cb + (size_t)idx*64;
  float s = 0.f;
  #pragma unroll
  for(int d=0; d<64; d++) s = fmaf(p[d], p[d], s);
  cb2[idx] = s;
}

// --------------------------- encoder first conv (C_in=1, K=4, s=2), bf16 ch-last
// out[b][l][co] = relu(bias[co] + sum_k w[co*4+k]*x[2l-1+k])
__global__ __launch_bounds__(256) void k_enc0(
    const float* __restrict__ x, const float* __restrict__ w,
    const float* __restrict__ bias, u16* __restrict__ out){
  const int co = threadIdx.x;
  const int b  = blockIdx.y;
  const int l0 = blockIdx.x*16;
  const float* xr = x + (size_t)b*NITEMS;
  float4 wv = *(const float4*)&w[co*4];
  float bv = bias[co];
  for(int dl=0; dl<16; dl++){
    int l = l0 + dl;
    int i0 = 2*l - 1;
    float x0 = (i0 >= 0) ? xr[i0] : 0.f;
    float x1 = xr[i0+1];
    float x2 = xr[i0+2];
    float x3 = (i0+3 < NITEMS) ? xr[i0+3] : 0.f;
    float acc = bv;
    acc = fmaf(wv.x, x0, acc); acc = fmaf(wv.y, x1, acc);
    acc = fmaf(wv.z, x2, acc); acc = fmaf(wv.w, x3, acc);
    out[((size_t)(b*LENC + l))*NHID + co] = f2b(fmaxf(acc, 0.f));
  }
}

// --------------------------------------------- generic implicit-GEMM conv (MFMA)
// in:  bf16 ch-last [b][L][CIN]
// wb:  bf16 [KK][COUT][CIN]  (tap-major)
// out: bf16 ch-last [b][L][COUT]   (CHF=0)
//      f32 ch-first [b][COUT][L]   (CHF=1, for z_e)
// RES: out += res (bf16 ch-last), pre-relu.
// block = 4 waves; wave grid WM x WN; wave computes 64co x 64l (4x4 16x16 tiles)
#define LP 40   // LDS row stride in bf16 (80B: 16B-aligned, odd bank groups)
template<int CIN, int COUT, int KK, int WM, int WN, int RELU, int RES, int CHF>
__global__ __launch_bounds__(256) void k_cgemm(
    const u16* __restrict__ in, const u16* __restrict__ wb,
    const float* __restrict__ bias, const u16* __restrict__ res,
    void* __restrict__ outv, int L){
  constexpr int CO_T = WM*64;
  constexpr int LT   = WN*64;
  constexpr int PAD  = (KK-1)/2;
  constexpr int RXS  = LT + KK - 1;
  __shared__ __align__(16) u16 sx[RXS][LP];
  __shared__ __align__(16) u16 sw[KK][CO_T][LP];

  const int tid = threadIdx.x;
  const int bb  = blockIdx.z;
  const int co0 = blockIdx.y*CO_T;
  const int l0  = blockIdx.x*LT;
  const int wave = tid>>6, lane = tid&63;
  const int wm = wave % WM, wn = wave / WM;
  const int quad = lane>>4, l16 = lane&15;

  f32x4 acc[4][4];
  #pragma unroll
  for(int m=0;m<4;m++)
    #pragma unroll
    for(int n=0;n<4;n++) acc[m][n] = (f32x4){0.f,0.f,0.f,0.f};

  for(int cib=0; cib<CIN; cib+=32){
    // stage activations: rows l0-PAD .. l0-PAD+RXS-1, 32 ci each (4x16B chunks)
    for(int s=tid; s<RXS*4; s+=256){
      int row = s>>2, ch = s&3;
      int l = l0 - PAD + row;
      int4 v;
      if(l >= 0 && l < L)
        v = *(const int4*)(in + ((size_t)(bb*L + l))*CIN + cib + ch*8);
      else
        v = make_int4(0,0,0,0);
      *(int4*)&sx[row][ch*8] = v;
    }
    // stage weights: [kk][co-tile][32ci]
    for(int s=tid; s<KK*CO_T*4; s+=256){
      int row = s>>2, ch = s&3;
      int kk = row / CO_T, cr = row % CO_T;
      int4 v = *(const int4*)(wb + ((size_t)(kk*COUT + co0 + cr))*CIN + cib + ch*8);
      *(int4*)&sw[kk][cr][ch*8] = v;
    }
    __syncthreads();
    #pragma unroll
    for(int kk=0; kk<KK; kk++){
      bf16x8 af[4];
      #pragma unroll
      for(int m=0;m<4;m++)
        af[m] = *(const bf16x8*)&sw[kk][wm*64 + m*16 + l16][quad*8];
      #pragma unroll
      for(int n=0;n<4;n++){
        bf16x8 bf = *(const bf16x8*)&sx[wn*64 + n*16 + l16 + kk][quad*8];
        #pragma unroll
        for(int m=0;m<4;m++)
          acc[m][n] = __builtin_amdgcn_mfma_f32_16x16x32_bf16(af[m], bf, acc[m][n], 0,0,0);
      }
    }
    __syncthreads();
  }

  // epilogue
  #pragma unroll
  for(int m=0;m<4;m++){
    int co4 = co0 + wm*64 + m*16 + quad*4;
    float4 bv = *(const float4*)&bias[co4];
    #pragma unroll
    for(int n=0;n<4;n++){
      int l = l0 + wn*64 + n*16 + l16;
      float v0 = acc[m][n][0] + bv.x;
      float v1 = acc[m][n][1] + bv.y;
      float v2 = acc[m][n][2] + bv.z;
      float v3 = acc[m][n][3] + bv.w;
      if(RES){
        ushort4 rv = *(const ushort4*)(res + ((size_t)(bb*L + l))*COUT + co4);
        v0 += b2f(rv.x); v1 += b2f(rv.y); v2 += b2f(rv.z); v3 += b2f(rv.w);
      }
      if(RELU){
        v0 = fmaxf(v0,0.f); v1 = fmaxf(v1,0.f); v2 = fmaxf(v2,0.f); v3 = fmaxf(v3,0.f);
      }
      if(CHF){
        float* of = (float*)outv;
        of[((size_t)(bb*COUT + co4+0))*L + l] = v0;
        of[((size_t)(bb*COUT + co4+1))*L + l] = v1;
        of[((size_t)(bb*COUT + co4+2))*L + l] = v2;
        of[((size_t)(bb*COUT + co4+3))*L + l] = v3;
      }else{
        u16* ob = (u16*)outv;
        ushort4 o;
        o.x = f2b(v0); o.y = f2b(v1); o.z = f2b(v2); o.w = f2b(v3);
        *(ushort4*)(ob + ((size_t)(bb*L + l))*COUT + co4) = o;
      }
    }
  }
}

// --------------------------------------------------- residual-VQ (all 4 stages)
// one thread per 64-elem row (torch view(-1,64): 64 consecutive L positions)
__global__ __launch_bounds__(256) void k_vq(
    const float* __restrict__ z_e, const float* __restrict__ cb,
    const float* __restrict__ cbs, const float* __restrict__ cb2,
    float* __restrict__ z_q, float* __restrict__ loss, int* __restrict__ counts){
  __shared__ int hist[NQ_][NEMB_];
  const int tid = threadIdx.x;
  for(int i=tid;i<NQ_*NEMB_;i+=256) (&hist[0][0])[i]=0;
  __syncthreads();

  const size_t row = (size_t)blockIdx.x*256 + tid;
  const float4* zp = (const float4*)(z_e + row*64);
  float r[64];
  #pragma unroll
  for(int i=0;i<16;i++){
    float4 v = zp[i];
    r[4*i+0]=v.x; r[4*i+1]=v.y; r[4*i+2]=v.z; r[4*i+3]=v.w;
  }

  #pragma unroll 1
  for(int q=0;q<NQ_;q++){
    float a0=0.f,a1=0.f,a2=0.f,a3=0.f;
    #pragma unroll
    for(int d=0;d<64;d+=4){
      a0=fmaf(r[d+0],r[d+0],a0); a1=fmaf(r[d+1],r[d+1],a1);
      a2=fmaf(r[d+2],r[d+2],a2); a3=fmaf(r[d+3],r[d+3],a3);
    }
    float rsq=(a0+a1)+(a2+a3);

    const float* cq  = cbs + (size_t)q*NEMB_*64;
    const float* c2q = cb2 + (size_t)q*NEMB_;
    float best=3.0e38f; int bi=0;
    #pragma unroll 2
    for(int c=0;c<NEMB_;c++){
      const float* cc = cq + c*64;           // wave-uniform -> s_load stream
      float s0=c2q[c], s1=0.f, s2=0.f, s3=0.f;
      #pragma unroll
      for(int d=0;d<64;d+=4){
        s0=fmaf(cc[d+0],r[d+0],s0);
        s1=fmaf(cc[d+1],r[d+1],s1);
        s2=fmaf(cc[d+2],r[d+2],s2);
        s3=fmaf(cc[d+3],r[d+3],s3);
      }
      float sc=(s0+s1)+(s2+s3);              // |c|^2 - 2 r.c
      if(sc<best){best=sc;bi=c;}             // strict < keeps first index on ties
    }
    float sl = rsq + best;                   // sum((quant-r)^2) = |r|^2 + best
    #pragma unroll
    for(int off=32;off;off>>=1) sl += __shfl_down(sl, off);
    if((tid&63)==0) atomicAdd(&loss[q], sl);
    atomicAdd(&hist[q][bi], 1);
    const float4* qp = (const float4*)(cb + ((size_t)q*NEMB_ + bi)*64);
    #pragma unroll
    for(int i=0;i<16;i++){
      float4 v = qp[i];
      r[4*i+0]-=v.x; r[4*i+1]-=v.y; r[4*i+2]-=v.z; r[4*i+3]-=v.w;
    }
  }
  float4* oq = (float4*)(z_q + row*64);
  #pragma unroll
  for(int i=0;i<16;i++){
    float4 v = zp[i];
    float4 w;
    w.x=v.x-r[4*i+0]; w.y=v.y-r[4*i+1]; w.z=v.z-r[4*i+2]; w.w=v.w-r[4*i+3];
    oq[i]=w;
  }
  __syncthreads();
  for(int i=tid;i<NQ_*NEMB_;i+=256){
    int v=(&hist[0][0])[i];
    if(v) atomicAdd(&counts[i], v);
  }
}

// -------------------- ConvTranspose1d K=4 s=2 p=1 (64->256) + relu, MFMA
// z_q: f32 ch-first [b][64][4096]; out: bf16 ch-last [b][8192][256]
// even j=2t: sum_ci w[ci,co,1]*x[t] + w[ci,co,3]*x[t-1]
// odd  j=2t+1: sum_ci w[ci,co,2]*x[t] + w[ci,co,0]*x[t+1]
__global__ __launch_bounds__(256) void k_convT(
    const float* __restrict__ zq, const u16* __restrict__ wb4,
    const float* __restrict__ bias, u16* __restrict__ out){
  __shared__ __align__(16) u16 sxT[66][LP];
  __shared__ __align__(16) u16 sw4[4][128][LP];
  const int tid = threadIdx.x;
  const int bb  = blockIdx.z;
  const int co0 = blockIdx.y*128;
  const int t0  = blockIdx.x*64;
  const int wave = tid>>6, lane = tid&63;
  const int wm = wave & 1, wn = wave >> 1;
  const int quad = lane>>4, l16 = lane&15;

  f32x4 ae[4][2], ao[4][2];
  #pragma unroll
  for(int m=0;m<4;m++)
    #pragma unroll
    for(int n=0;n<2;n++){ ae[m][n]=(f32x4){0,0,0,0}; ao[m][n]=(f32x4){0,0,0,0}; }

  for(int cib=0; cib<NLAT; cib+=32){
    // stage x^T: rows t0-1..t0+64, 32 ci (fp32 -> bf16, transpose)
    for(int s=tid; s<66*32; s+=256){
      int ci = s/66, tt = s%66;
      int t = t0 - 1 + tt;
      float v = 0.f;
      if(t >= 0 && t < LENC) v = zq[((size_t)(bb*NLAT + cib + ci))*LENC + t];
      sxT[tt][ci] = f2b(v);
    }
    // stage weights: 4 taps x 128 co x 32 ci
    for(int s=tid; s<4*128*4; s+=256){
      int row = s>>2, ch = s&3;
      int tap = row>>7, cr = row&127;
      int4 v = *(const int4*)(wb4 + ((size_t)(tap*NHID + co0 + cr))*NLAT + cib + ch*8);
      *(int4*)&sw4[tap][cr][ch*8] = v;
    }
    __syncthreads();
    #pragma unroll
    for(int m=0;m<4;m++){
      int crow = wm*64 + m*16 + l16;
      bf16x8 a0 = *(const bf16x8*)&sw4[0][crow][quad*8];
      bf16x8 a1 = *(const bf16x8*)&sw4[1][crow][quad*8];
      bf16x8 a2 = *(const bf16x8*)&sw4[2][crow][quad*8];
      bf16x8 a3 = *(const bf16x8*)&sw4[3][crow][quad*8];
      #pragma unroll
      for(int n=0;n<2;n++){
        int off = wn*32 + n*16 + l16;
        bf16x8 bm = *(const bf16x8*)&sxT[off  ][quad*8];   // x[t-1]
        bf16x8 b0 = *(const bf16x8*)&sxT[off+1][quad*8];   // x[t]
        bf16x8 bp = *(const bf16x8*)&sxT[off+2][quad*8];   // x[t+1]
        ae[m][n] = __builtin_amdgcn_mfma_f32_16x16x32_bf16(a1, b0, ae[m][n], 0,0,0);
        ae[m][n] = __builtin_amdgcn_mfma_f32_16x16x32_bf16(a3, bm, ae[m][n], 0,0,0);
        ao[m][n] = __builtin_amdgcn_mfma_f32_16x16x32_bf16(a2, b0, ao[m][n], 0,0,0);
        ao[m][n] = __builtin_amdgcn_mfma_f32_16x16x32_bf16(a0, bp, ao[m][n], 0,0,0);
      }
    }
    __syncthreads();
  }

  #pragma unroll
  for(int m=0;m<4;m++){
    int co4 = co0 + wm*64 + m*16 + quad*4;
    float4 bv = *(const float4*)&bias[co4];
    #pragma unroll
    for(int n=0;n<2;n++){
      int t = t0 + wn*32 + n*16 + l16;
      int je = 2*t, jo = 2*t+1;
      ushort4 oe, oo;
      oe.x = f2b(fmaxf(ae[m][n][0]+bv.x, 0.f));
      oe.y = f2b(fmaxf(ae[m][n][1]+bv.y, 0.f));
      oe.z = f2b(fmaxf(ae[m][n][2]+bv.z, 0.f));
      oe.w = f2b(fmaxf(ae[m][n][3]+bv.w, 0.f));
      oo.x = f2b(fmaxf(ao[m][n][0]+bv.x, 0.f));
      oo.y = f2b(fmaxf(ao[m][n][1]+bv.y, 0.f));
      oo.z = f2b(fmaxf(ao[m][n][2]+bv.z, 0.f));
      oo.w = f2b(fmaxf(ao[m][n][3]+bv.w, 0.f));
      *(ushort4*)(out + ((size_t)(bb*LDEC + je))*NHID + co4) = oe;
      *(ushort4*)(out + ((size_t)(bb*LDEC + jo))*NHID + co4) = oo;
    }
  }
}

// -------------------- final ConvTranspose K=3 s=1 p=1 (256->1), f32 out
// dvec[b,j] = b0 + sum_ci( w[ci*3+2]*d[j-1] + w[ci*3+1]*d[j] + w[ci*3+0]*d[j+1] )
__global__ __launch_bounds__(256) void k_finalT(
    const u16* __restrict__ in, const float* __restrict__ w,
    const float* __restrict__ bias, float* __restrict__ out){
  __shared__ u16 sd[66][258];
  __shared__ float red[4][64];
  const int tid = threadIdx.x;
  const int j0 = blockIdx.x*64;
  const int bb = blockIdx.y;
  // stage rows j0-1 .. j0+64 (256 ci each)
  for(int s=tid; s<66*32; s+=256){
    int row = s>>5, ch = s&31;
    int l = j0 - 1 + row;
    int4 v = make_int4(0,0,0,0);
    if(l >= 0 && l < LDEC)
      v = *(const int4*)(in + ((size_t)(bb*LDEC + l))*NHID + ch*8);
    // scalar int writes (row stride 258 u16 = 516B, not 16B aligned)
    int* dst = (int*)&sd[row][ch*8];
    dst[0]=v.x; dst[1]=v.y; dst[2]=v.z; dst[3]=v.w;
  }
  __syncthreads();
  const int jl = tid & 63;
  const int part = tid >> 6;   // wave-uniform
  float acc = 0.f;
  for(int ci=0; ci<64; ci++){
    int cg = part*64 + ci;
    float w0 = w[cg*3+2], w1 = w[cg*3+1], w2 = w[cg*3+0];
    acc = fmaf(w0, b2f(sd[jl  ][cg]), acc);
    acc = fmaf(w1, b2f(sd[jl+1][cg]), acc);
    acc = fmaf(w2, b2f(sd[jl+2][cg]), acc);
  }
  red[part][jl] = acc;
  __syncthreads();
  if(tid < 64)
    out[(size_t)bb*NITEMS + j0 + tid] =
      bias[0] + red[0][tid] + red[1][tid] + red[2][tid] + red[3][tid];
}

// ------------------------------------ out projection: recon = dvec @ W^T + b
__global__ __launch_bounds__(256) void k_outproj(
    const float* __restrict__ dvec, const float* __restrict__ Wm,
    const float* __restrict__ bias, float* __restrict__ out){
  __shared__ float s_d[32][129];   // [m][b]
  __shared__ float s_w[32][65];    // [m][n]
  const int tid = threadIdx.x;
  const int n_base = blockIdx.x*64;
  const int n_grp = tid>>4;        // 0..15
  const int b_grp = tid&15;        // 0..15
  float acc[4][8];
  #pragma unroll
  for(int k=0;k<4;k++)
    #pragma unroll
    for(int j=0;j<8;j++) acc[k][j]=0.f;

  const int mloc = tid&31;
  const int half = tid>>5;         // 0..7
  for(int m0=0; m0<NITEMS; m0+=32){
    #pragma unroll
    for(int r=0;r<16;r++){
      int bbv = half + r*8;
      s_d[mloc][bbv] = dvec[(size_t)bbv*NITEMS + m0 + mloc];
    }
    #pragma unroll
    for(int r=0;r<8;r++){
      int nn = half + r*8;
      s_w[mloc][nn] = Wm[(size_t)(n_base+nn)*NITEMS + m0 + mloc];
    }
    __syncthreads();
    for(int m=0;m<32;m++){
      float wv[4], dv[8];
      #pragma unroll
      for(int k=0;k<4;k++) wv[k]=s_w[m][n_grp+16*k];
      #pragma unroll
      for(int j=0;j<8;j++) dv[j]=s_d[m][b_grp+16*j];
      #pragma unroll
      for(int k=0;k<4;k++)
        #pragma unroll
        for(int j=0;j<8;j++)
          acc[k][j]=fmaf(wv[k],dv[j],acc[k][j]);
    }
    __syncthreads();
  }
  #pragma unroll
  for(int k=0;k<4;k++){
    int n = n_base + n_grp + 16*k;
    float bv = bias[n];
    #pragma unroll
    for(int j=0;j<8;j++){
      int bbv = b_grp + 16*j;
      out[(size_t)bbv*NITEMS + n] = acc[k][j] + bv;
    }
  }
}

// ------------------------------------------------- finalize scalars
__global__ void k_finalize(const float* __restrict__ loss, const int* __restrict__ counts,
                           float* __restrict__ out){
  __shared__ float sh[512];
  const int tid = threadIdx.x;
  float perp_sum = 0.f;
  for(int q=0;q<NQ_;q++){
    float avg = (float)counts[q*NEMB_+tid] / (float)NROWS;
    sh[tid] = avg*logf(avg + 1e-10f);
    __syncthreads();
    for(int s=256;s>0;s>>=1){ if(tid<s) sh[tid]+=sh[tid+s]; __syncthreads(); }
    if(tid==0) perp_sum += expf(-sh[0]);
    __syncthreads();
  }
  if(tid==0){
    float vl = 0.f;
    for(int q=0;q<NQ_;q++) vl += 1.25f*loss[q]/VQ_NELEM;
    out[0] = vl;
    out[1] = perp_sum/(float)NQ_;
  }
}

// =================================================================== launcher
extern "C" void kernel_launch(void* const* d_in, const int* in_sizes, int n_in,
                              void* d_out, int out_size, void* d_ws, size_t ws_size,
                              hipStream_t stream){
  (void)in_sizes; (void)n_in; (void)out_size;
  const int*   uid   = (const int*)d_in[0];
  const float* mat   = (const float*)d_in[1];
  const float* ec_w  = (const float*)d_in[2];
  const float* ec_b  = (const float*)d_in[3];
  const float* er_w1 = (const float*)d_in[4];
  const float* er_b1 = (const float*)d_in[5];
  const float* er_w2 = (const float*)d_in[6];
  const float* er_b2 = (const float*)d_in[7];
  const float* ef_w  = (const float*)d_in[8];
  const float* ef_b  = (const float*)d_in[9];
  const float* cb    = (const float*)d_in[10];
  const float* dt_w  = (const float*)d_in[11];
  const float* dt_b  = (const float*)d_in[12];
  const float* dr_w1 = (const float*)d_in[13];
  const float* dr_b1 = (const float*)d_in[14];
  const float* dr_w2 = (const float*)d_in[15];
  const float* dr_b2 = (const float*)d_in[16];
  const float* df_w  = (const float*)d_in[17];
  const float* df_b  = (const float*)d_in[18];
  const float* op_w  = (const float*)d_in[19];
  const float* op_b  = (const float*)d_in[20];
  float* outp = (float*)d_out;

  // ---------------- workspace: fixed region, then chunk buffers
  float* W = (float*)d_ws;
  size_t o = 0;
  float* xg    = W + o; o += (size_t)NB*NITEMS;
  float* dvec  = W + o; o += (size_t)NB*NITEMS;
  u16* wb3e0 = (u16*)(W + o); o += 3*NHID*NHID/2;
  u16* wb3e1 = (u16*)(W + o); o += 3*NHID*NHID/2;
  u16* wb3d0 = (u16*)(W + o); o += 3*NHID*NHID/2;
  u16* wb3d1 = (u16*)(W + o); o += 3*NHID*NHID/2;
  u16* wbF   = (u16*)(W + o); o += 3*NLAT*NHID/2;
  u16* wb1e0 = (u16*)(W + o); o += NHID*NHID/2;
  u16* wb1e1 = (u16*)(W + o); o += NHID*NHID/2;
  u16* wb1d0 = (u16*)(W + o); o += NHID*NHID/2;
  u16* wb1d1 = (u16*)(W + o); o += NHID*NHID/2;
  u16* wbT   = (u16*)(W + o); o += 4*NLAT*NHID/2;
  float* cbs   = W + o; o += (size_t)NQ_*NEMB_*64;
  float* cb2   = W + o; o += NQ_*NEMB_;
  float* lossb = W + o; o += 4;
  int*   counts= (int*)(W + o); o += NQ_*NEMB_;
  const size_t fixedF = o;

  // chunk buffers: two bf16 act buffers of CB*LDEC*NHID u16 each
  const size_t perBF = (size_t)LDEC*NHID/2;     // floats per batch elem per buffer
  size_t availF = ws_size/sizeof(float) > fixedF ? ws_size/sizeof(float) - fixedF : 0;
  int CB = 128;
  while(CB > 1 && (size_t)CB*2*perBF > availF) CB >>= 1;

  k_zero<<<(4 + NQ_*NEMB_ + 255)/256,256,0,stream>>>(lossb, 4 + NQ_*NEMB_);

  // weight packs (fp32 -> bf16, tap-major [k][co][ci])
  k_packw<<<(3*NHID*NHID+255)/256,256,0,stream>>>(er_w1,             wb3e0, NHID, NHID, 3);
  k_packw<<<(3*NHID*NHID+255)/256,256,0,stream>>>(er_w1+3*NHID*NHID, wb3e1, NHID, NHID, 3);
  k_packw<<<(3*NHID*NHID+255)/256,256,0,stream>>>(dr_w1,             wb3d0, NHID, NHID, 3);
  k_packw<<<(3*NHID*NHID+255)/256,256,0,stream>>>(dr_w1+3*NHID*NHID, wb3d1, NHID, NHID, 3);
  k_packw<<<(3*NLAT*NHID+255)/256,256,0,stream>>>(ef_w,              wbF,   NLAT, NHID, 3);
  k_packw<<<(NHID*NHID+255)/256,256,0,stream>>>(er_w2,               wb1e0, NHID, NHID, 1);
  k_packw<<<(NHID*NHID+255)/256,256,0,stream>>>(er_w2+NHID*NHID,     wb1e1, NHID, NHID, 1);
  k_packw<<<(NHID*NHID+255)/256,256,0,stream>>>(dr_w2,               wb1d0, NHID, NHID, 1);
  k_packw<<<(NHID*NHID+255)/256,256,0,stream>>>(dr_w2+NHID*NHID,     wb1d1, NHID, NHID, 1);
  k_packwT<<<(4*NLAT*NHID+255)/256,256,0,stream>>>(dt_w, wbT);
  k_cbprep<<<(NQ_*NEMB_*64)/256,256,0,stream>>>(cb, cbs);
  k_cbnorm<<<(NQ_*NEMB_+255)/256,256,0,stream>>>(cb, cb2);

  k_gather<<<dim3(NITEMS/256, NB),256,0,stream>>>(uid, mat, xg);

  u16* D0b = (u16*)(W + fixedF);
  u16* D1b = D0b + (size_t)CB*LDEC*NHID;

  for(int c0 = 0; c0 < NB; c0 += CB){
    u16* E0 = D0b;                                  // [CB][4096][256] bf16
    u16* E1 = D0b + (size_t)CB*LENC*NHID;
    float* z_e = (float*)D1b;                       // [CB][64][4096] f32
    float* z_q = z_e + (size_t)CB*NLAT*LENC;
    const float* xgc = xg + (size_t)c0*NITEMS;
    float* dvc = dvec + (size_t)c0*NITEMS;

    // ---- encoder
    k_enc0<<<dim3(LENC/16, CB),256,0,stream>>>(xgc, ec_w, ec_b, E0);
    k_cgemm<256,256,3,2,2,1,0,0><<<dim3(LENC/128, 2, CB),256,0,stream>>>(E0, wb3e0, er_b1,      nullptr, E1, LENC);
    k_cgemm<256,256,1,2,2,1,1,0><<<dim3(LENC/128, 2, CB),256,0,stream>>>(E1, wb1e0, er_b2,      E0,      E0, LENC);
    k_cgemm<256,256,3,2,2,1,0,0><<<dim3(LENC/128, 2, CB),256,0,stream>>>(E0, wb3e1, er_b1+NHID, nullptr, E1, LENC);
    k_cgemm<256,256,1,2,2,1,1,0><<<dim3(LENC/128, 2, CB),256,0,stream>>>(E1, wb1e1, er_b2+NHID, E0,      E0, LENC);
    k_cgemm<256, 64,3,1,4,0,0,1><<<dim3(LENC/256, 1, CB),256,0,stream>>>(E0, wbF,   ef_b,       nullptr, z_e, LENC);

    // ---- residual VQ
    k_vq<<<(CB*NLAT*LENC/64)/256,256,0,stream>>>(z_e, cb, cbs, cb2, z_q, lossb, counts);

    // ---- decoder
    k_convT<<<dim3(LENC/64, 2, CB),256,0,stream>>>(z_q, wbT, dt_b, D0b);
    k_cgemm<256,256,3,2,2,1,0,0><<<dim3(LDEC/128, 2, CB),256,0,stream>>>(D0b, wb3d0, dr_b1,      nullptr, D1b, LDEC);
    k_cgemm<256,256,1,2,2,1,1,0><<<dim3(LDEC/128, 2, CB),256,0,stream>>>(D1b, wb1d0, dr_b2,      D0b,     D0b, LDEC);
    k_cgemm<256,256,3,2,2,1,0,0><<<dim3(LDEC/128, 2, CB),256,0,stream>>>(D0b, wb3d1, dr_b1+NHID, nullptr, D1b, LDEC);
    k_cgemm<256,256,1,2,2,1,1,0><<<dim3(LDEC/128, 2, CB),256,0,stream>>>(D1b, wb1d1, dr_b2+NHID, D0b,     D0b, LDEC);
    k_finalT<<<dim3(LDEC/64, CB),256,0,stream>>>(D0b, df_w, df_b, dvc);
  }

  // ---- head + scalars
  k_outproj<<<NITEMS/64,256,0,stream>>>(dvec, op_w, op_b, outp);
  k_finalize<<<1,512,0,stream>>>(lossb, counts, outp + (size_t)NB*NITEMS);
}